// Round 12
// baseline (186.641 us; speedup 1.0000x reference)
//
#include <hip/hip_runtime.h>
#include <stdint.h>

// ---------------------------------------------------------------------------
// MAB block: O = LN2(O1 + relu(O1@Wo+bo)), O1 = LN1(Q + MHA(Q,K,V,mask))
// ---------------------------------------------------------------------------

typedef unsigned short u16;
typedef unsigned int u32;
typedef __attribute__((ext_vector_type(8))) short s16x8;   // bf16x8 frag (4 VGPR)
typedef __attribute__((ext_vector_type(4))) float f32x4;
typedef __attribute__((ext_vector_type(16))) float f32x16; // 32x32 MFMA C/D
typedef __attribute__((ext_vector_type(4))) u16 u16x4;
typedef __attribute__((ext_vector_type(4))) u32 u32x4;

typedef __attribute__((address_space(1))) const void* as1cv;
typedef __attribute__((address_space(3))) void* as3v;

#define DEVINL __device__ __forceinline__

DEVINL u16 f2bf(float f) {
  union { float f; u32 u; } v; v.f = f;
  return (u16)((v.u + 0x7FFFu + ((v.u >> 16) & 1u)) >> 16);  // RNE
}
DEVINL float bf2f(u16 x) {
  union { u32 u; float f; } v; v.u = ((u32)x) << 16;
  return v.f;
}
DEVINL u32 cvtpk_bf16(float lo, float hi) {  // packed RNE f32x2 -> bf16x2
  u32 r;
  asm("v_cvt_pk_bf16_f32 %0, %1, %2" : "=v"(r) : "v"(lo), "v"(hi));
  return r;
}
DEVINL float fexp2(float x) {  // raw v_exp_f32 (2^x)
  float r;
  asm("v_exp_f32 %0, %1" : "=v"(r) : "v"(x));
  return r;
}
DEVINL void gload_lds16(const void* g, void* l) {
  __builtin_amdgcn_global_load_lds((as1cv)g, (as3v)l, 16, 0, 0);
}
DEVINL f32x16 mfma32(s16x8 a, s16x8 b, f32x16 c) {
  return __builtin_amdgcn_mfma_f32_32x32x16_bf16(a, b, c, 0, 0, 0);
}
template <int N> DEVINL void wait_vm() {
  asm volatile("s_waitcnt vmcnt(%0)" :: "i"(N) : "memory");
  __builtin_amdgcn_sched_barrier(0);
}
DEVINL void wait_lgkm0() {
  asm volatile("s_waitcnt lgkmcnt(0)" ::: "memory");
  __builtin_amdgcn_sched_barrier(0);
}
DEVINL void barrier_raw() {
  __builtin_amdgcn_sched_barrier(0);
  __builtin_amdgcn_s_barrier();
  __builtin_amdgcn_sched_barrier(0);
}

// ---------------------------------------------------------------------------
// fused preprocessing (one launch):
//   blocks [0,2048)     : grid-stride f32->bf16 convert of X,Y
//   blocks [2048,6144)  : 4x weight transpose+convert W[k][n] -> Wt[n][k]
//   blocks [6144,6176)  : mask prep -> pre-folded softmax bias
// ---------------------------------------------------------------------------
__global__ __launch_bounds__(256) void prep_all(
    const float* __restrict__ X, u16* __restrict__ Xbf,
    const float* __restrict__ Y, u16* __restrict__ Ybf,
    const float* __restrict__ W0, const float* __restrict__ W1,
    const float* __restrict__ W2, const float* __restrict__ W3,
    u16* __restrict__ T0, u16* __restrict__ T1,
    u16* __restrict__ T2, u16* __restrict__ T3,
    const u32* __restrict__ mraw, float* __restrict__ maskb) {
  const int bid = blockIdx.x;
  const int t = threadIdx.x;
  if (bid < 2048) {
    const int base = bid * 256 + t;
#pragma unroll
    for (int k = 0; k < 4; ++k) {
      int e0 = (base + k * 524288) * 2;
      const float* in = X;
      u16* out = Xbf;
      if (e0 >= 2097152) { e0 -= 2097152; in = Y; out = Ybf; }
      float4 v0 = *(const float4*)(in + (size_t)e0 * 4);
      float4 v1 = *(const float4*)(in + (size_t)e0 * 4 + 4);
      u32x4 o;
      o[0] = cvtpk_bf16(v0.x, v0.y);
      o[1] = cvtpk_bf16(v0.z, v0.w);
      o[2] = cvtpk_bf16(v1.x, v1.y);
      o[3] = cvtpk_bf16(v1.z, v1.w);
      *(u32x4*)(out + (size_t)e0 * 4) = o;
    }
    return;
  }
  if (bid < 6144) {
    const int r = bid - 2048;
    const int z = r >> 10, tile = r & 1023;
    const int bx = tile & 31, by = tile >> 5;
    const float* W = (z == 0) ? W0 : (z == 1) ? W1 : (z == 2) ? W2 : W3;
    u16* T = (z == 0) ? T0 : (z == 1) ? T1 : (z == 2) ? T2 : T3;
    __shared__ float tl[32][33];
    const int tx = t & 31, ty = t >> 5;
    const int N0 = bx << 5, K0 = by << 5;
#pragma unroll
    for (int i = 0; i < 4; ++i)
      tl[ty + i * 8][tx] = W[(size_t)(K0 + ty + i * 8) * 1024 + N0 + tx];
    __syncthreads();
#pragma unroll
    for (int i = 0; i < 4; ++i)
      T[(size_t)(N0 + ty + i * 8) * 1024 + K0 + tx] = f2bf(tl[tx][ty + i * 8]);
    return;
  }
  // ---- mask prep
  __shared__ int mode;
  int fB = 0, fF = 0;
  for (int i = t; i < 2048; i += 256) {
    u32 v = mraw[i];
    if (v == 0x3F800000u) fF = 1;
    else if (v > 1u) fB = 1;
  }
  if (t == 0) mode = 0;
  __syncthreads();
  if (fB) atomicOr(&mode, 1);
  if (fF) atomicOr(&mode, 2);
  __syncthreads();
  const int md = mode;
  const int idx = (bid - 6144) * 256 + t;
  int v;
  if (md & 1)       v = ((const unsigned char*)mraw)[idx] != 0;
  else if (md & 2)  v = ((const float*)mraw)[idx] != 0.0f;
  else              v = ((const int*)mraw)[idx] != 0;
  maskb[idx] = v ? -3e30f : -11.54156032f;
}

// ---------------------------------------------------------------------------
// GEMM v2 (mfma32, 256x128 block tile, 4 waves x 128x64/wave, BK=64):
// Raises FLOP/LDS-read 1.33x over the 16x16 path (which measured LDS-pipe-
// bound at MfmaUtil 38.9% == model's 38.4%). LDS pair-interleaved 256B rows
// (two m-rows per LDS row, 16-slot XOR swizzle -> conflict-free b128 reads;
// same map as attn's V, measured 0 conflicts). 2-barrier K-loop (r8-proven).
// A/B frag: lane&31 = row, k = ks*16 + (lane>>5)*8. C/D: col=lane&31,
// row = (r&3)+8*(r>>2)+4*(lane>>5).
// LDS: lA 32KB (128 Prows x 256B) + lB 16KB = 48KB.
// ---------------------------------------------------------------------------
#define G32_FRAG(LDSP, PV, CB)                                                \
  (*(const s16x8*)((const char*)(LDSP) + (PV) * 256 +                         \
                   (((CB)) ^ (((PV) & 15) << 4))))

#define G32_SETUP                                                             \
  const int tid = threadIdx.x;                                                \
  const int w = tid >> 6, l = tid & 63;                                       \
  const int wm = w >> 1, wn = w & 1;                                          \
  const int q32 = l & 31, hi = l >> 5;                                        \
  int soA[8], soB[4];                                                         \
  _Pragma("unroll")                                                           \
  for (int c = 0; c < 8; ++c) {                                               \
    int P = (w * 8 + c) * 4 + (l >> 4);                                       \
    int u = (l & 15) ^ (P & 15);                                              \
    soA[c] = (2 * P + (u >> 3)) * 2048 + (u & 7) * 16;                        \
  }                                                                           \
  _Pragma("unroll")                                                           \
  for (int c = 0; c < 4; ++c) {                                               \
    int P = (w * 4 + c) * 4 + (l >> 4);                                       \
    int u = (l & 15) ^ (P & 15);                                              \
    soB[c] = (2 * P + (u >> 3)) * 2048 + (u & 7) * 16;                        \
  }                                                                           \
  int PA[4], PB[2];                                                           \
  _Pragma("unroll")                                                           \
  for (int mi = 0; mi < 4; ++mi) PA[mi] = wm * 64 + mi * 16 + (q32 >> 1);     \
  _Pragma("unroll")                                                           \
  for (int nj = 0; nj < 2; ++nj) PB[nj] = wn * 32 + nj * 16 + (q32 >> 1);     \
  const int c0 = (q32 & 1) * 128 + hi * 16;                                   \
  f32x16 acc[4][2];                                                           \
  _Pragma("unroll")                                                           \
  for (int i = 0; i < 4; ++i)                                                 \
    _Pragma("unroll")                                                         \
    for (int j = 0; j < 2; ++j)                                               \
      _Pragma("unroll")                                                       \
      for (int r = 0; r < 16; ++r) acc[i][j][r] = 0.f;

#define G32_STAGE(KT)                                                         \
  {                                                                           \
    const char* pa_ = gA + (size_t)(KT)*128;                                  \
    const char* pb_ = gB + (size_t)(KT)*128;                                  \
    _Pragma("unroll")                                                         \
    for (int c = 0; c < 8; ++c)                                               \
      gload_lds16(pa_ + soA[c], (char*)lA + (w * 8 + c) * 1024);              \
    _Pragma("unroll")                                                         \
    for (int c = 0; c < 4; ++c)                                               \
      gload_lds16(pb_ + soB[c], (char*)lB + (w * 4 + c) * 1024);              \
  }

#define G32_KLOOP                                                             \
  G32_STAGE(0)                                                                \
  __syncthreads();                                                            \
  for (int kt = 0; kt < 16; ++kt) {                                           \
    s16x8 af[4][2], bfg[2][2];                                                \
    _Pragma("unroll")                                                         \
    for (int ks = 0; ks < 2; ++ks) {                                          \
      _Pragma("unroll")                                                       \
      for (int mi = 0; mi < 4; ++mi)                                          \
        af[mi][ks] = G32_FRAG(lA, PA[mi], c0 + ks * 32);                      \
      _Pragma("unroll")                                                       \
      for (int nj = 0; nj < 2; ++nj)                                          \
        bfg[nj][ks] = G32_FRAG(lB, PB[nj], c0 + ks * 32);                     \
    }                                                                         \
    _Pragma("unroll")                                                         \
    for (int ks = 0; ks < 2; ++ks)                                            \
      _Pragma("unroll")                                                       \
      for (int mi = 0; mi < 4; ++mi)                                          \
        _Pragma("unroll")                                                     \
        for (int nj = 0; nj < 2; ++nj)                                        \
          acc[mi][nj] = mfma32(af[mi][ks], bfg[nj][ks], acc[mi][nj]);         \
    _Pragma("unroll")                                                         \
    for (int ks = 0; ks < 2; ++ks) {                                          \
      _Pragma("unroll")                                                       \
      for (int mi = 0; mi < 4; ++mi)                                          \
        af[mi][ks] = G32_FRAG(lA, PA[mi], c0 + 64 + ks * 32);                 \
      _Pragma("unroll")                                                       \
      for (int nj = 0; nj < 2; ++nj)                                          \
        bfg[nj][ks] = G32_FRAG(lB, PB[nj], c0 + 64 + ks * 32);                \
    }                                                                         \
    wait_lgkm0();                                                             \
    barrier_raw();                                                            \
    if (kt < 15) { G32_STAGE(kt + 1) }                                        \
    _Pragma("unroll")                                                         \
    for (int ks = 0; ks < 2; ++ks)                                            \
      _Pragma("unroll")                                                       \
      for (int mi = 0; mi < 4; ++mi)                                          \
        _Pragma("unroll")                                                     \
        for (int nj = 0; nj < 2; ++nj)                                        \
          acc[mi][nj] = mfma32(af[mi][ks], bfg[nj][ks], acc[mi][nj]);         \
    __syncthreads();                                                          \
  }

// merged Q/K/V GEMM: 768 blocks; g = id/256 selects gemm.
__global__ __launch_bounds__(256, 2) void gemm_qkv(
    const u16* __restrict__ Xbf, const u16* __restrict__ Ybf,
    const u16* __restrict__ Wqt, const u16* __restrict__ Wkt,
    const u16* __restrict__ Wvt,
    const float* __restrict__ bq, const float* __restrict__ bk,
    const float* __restrict__ bv,
    u16* __restrict__ Qbf, u16* __restrict__ Kbf, u16* __restrict__ Vt) {
  __shared__ u16 lA[16384];  // 32KB
  __shared__ u16 lB[8192];   // 16KB

  const int id = blockIdx.x;
  const int g = id >> 8;            // 0=Q, 1=K, 2=V
  const int sub = id & 255;
  const int swz = (sub & 7) * 32 + (sub >> 3);   // XCD-contiguous per gemm
  const int mb = swz >> 3;          // 0..31
  const int nb = swz & 7;           // 0..7

  const u16* A    = (g == 0) ? Xbf : Ybf;
  const u16* Bt   = (g == 0) ? Wqt : (g == 1) ? Wkt : Wvt;
  const float* bias = (g == 0) ? bq : (g == 1) ? bk : bv;

  G32_SETUP
  const char* gA = (const char*)A + (size_t)(mb * 256) * 2048;
  const char* gB = (const char*)Bt + (size_t)(nb * 128) * 2048;

  G32_KLOOP

  const int growb = mb * 256 + wm * 128;
  const int gcolb = nb * 128 + wn * 64;

  if (g == 2) {
#pragma unroll
    for (int nj = 0; nj < 2; ++nj) {
      const int gcol = gcolb + nj * 32 + q32;
      const float bsv = bias[gcol];
#pragma unroll
      for (int mi = 0; mi < 4; ++mi) {
#pragma unroll
        for (int rq = 0; rq < 4; ++rq) {
          const int row0 = growb + mi * 32 + rq * 8 + hi * 4;
          u16x4 pk;
#pragma unroll
          for (int i = 0; i < 4; ++i) pk[i] = f2bf(acc[mi][nj][rq * 4 + i] + bsv);
          size_t flat = ((size_t)((row0 >> 10) << 10) + gcol) * 1024 + (row0 & 1023);
          *(u16x4*)(Vt + flat) = pk;
        }
      }
    }
  } else {
    u16* outBF = g ? Kbf : Qbf;
#pragma unroll
    for (int nj = 0; nj < 2; ++nj) {
      const int gcol = gcolb + nj * 32 + q32;
      const float bsv = bias[gcol];
#pragma unroll
      for (int mi = 0; mi < 4; ++mi) {
#pragma unroll
        for (int rq = 0; rq < 4; ++rq) {
          const int row0 = growb + mi * 32 + rq * 8 + hi * 4;
#pragma unroll
          for (int i = 0; i < 4; ++i)
            outBF[(size_t)(row0 + i) * 1024 + gcol] = f2bf(acc[mi][nj][rq * 4 + i] + bsv);
        }
      }
    }
  }
}

// O-projection GEMM: 256 blocks. outBF = bf16(bf2f(resid) + relu(acc+bias))
__global__ __launch_bounds__(256, 2) void gemm_o(
    const u16* __restrict__ A, const u16* __restrict__ Bt,
    const float* __restrict__ bias, u16* __restrict__ outBF,
    const u16* __restrict__ residBF) {
  __shared__ u16 lA[16384];
  __shared__ u16 lB[8192];

  const int id = blockIdx.x;
  const int swz = (id & 7) * 32 + (id >> 3);
  const int mb = swz >> 3;
  const int nb = swz & 7;

  G32_SETUP
  const char* gA = (const char*)A + (size_t)(mb * 256) * 2048;
  const char* gB = (const char*)Bt + (size_t)(nb * 128) * 2048;

  G32_KLOOP

  const int growb = mb * 256 + wm * 128;
  const int gcolb = nb * 128 + wn * 64;

#pragma unroll
  for (int nj = 0; nj < 2; ++nj) {
    const int gcol = gcolb + nj * 32 + q32;
    const float bsv = bias[gcol];
#pragma unroll
    for (int mi = 0; mi < 4; ++mi) {
#pragma unroll
      for (int rq = 0; rq < 4; ++rq) {
        const int row0 = growb + mi * 32 + rq * 8 + hi * 4;
#pragma unroll
        for (int i = 0; i < 4; ++i) {
          size_t idx = (size_t)(row0 + i) * 1024 + gcol;
          outBF[idx] = f2bf(bf2f(residBF[idx]) +
                            fmaxf(acc[mi][nj][rq * 4 + i] + bsv, 0.f));
        }
      }
    }
  }
}

// ---------------------------------------------------------------------------
// flash attention v8 (unchanged): counted-vmcnt pipeline, K dbuf + V single-
// buffered pair-interleaved, swapped QK^T 32x32x16, static-max softmax,
// per-chunk P packing, permlane32_swap. grid 512; bh per XCD.
// ---------------------------------------------------------------------------
__global__ __launch_bounds__(256, 2) void attn_fwd(
    const u16* __restrict__ Qbf, const u16* __restrict__ Kbf,
    const u16* __restrict__ Vt, const float* __restrict__ maskb,
    u16* __restrict__ attnO) {
  __shared__ u16 lK[2][64 * 128];  // 2x16KB [key][d] 256B rows, swz (key&15)<<4
  __shared__ u16 lV[128 * 64];     // 16KB pair-interleaved
  __shared__ float lM[1024];       // 4KB pre-folded softmax bias

  const int id = blockIdx.x;
  const int xcd = id & 7, seq = id >> 3;
  const int bh = xcd * 8 + (seq >> 3);   // all qb of a bh stay on one XCD
  const int qb = seq & 7;
  const int b = bh >> 3, h = bh & 7;
  const int tid = threadIdx.x;
  const int w = tid >> 6, l = tid & 63;
  const int q32 = l & 31, hi = l >> 5;

  const u16* Qrow = Qbf + ((size_t)(b * 1024 + qb * 128 + w * 32 + q32)) * 1024 + h * 128;
  s16x8 qf[8];
#pragma unroll
  for (int dc = 0; dc < 8; ++dc) qf[dc] = *(const s16x8*)(Qrow + dc * 16 + hi * 8);

  const int srK = l >> 4, slK = l & 15;
  int soK[4], soV[4];
#pragma unroll
  for (int c = 0; c < 4; ++c) {
    int rowK = (w * 4 + c) * 4 + srK;
    soK[c] = rowK * 2048 + ((slK << 4) ^ ((rowK & 15) << 4));
    int pairid = (w * 4 + c) * 4 + (l >> 4);
    int u = (l & 15) ^ (pairid & 15);
    int d = pairid * 2 + (u >> 3);
    soV[c] = d * 2048 + (u & 7) * 16;   // + t*128 bytes at stage time
  }
  const char* pgK = (const char*)(Kbf + ((size_t)(b * 1024)) * 1024 + h * 128);
  const char* pgV = (const char*)(Vt + ((size_t)(b * 1024 + h * 128)) * 1024);

  const int bK = q32 * 256;
  const int swzK = (q32 & 15) << 4;
  const int hib = hi * 16;
  int loV[4];
#pragma unroll
  for (int c = 0; c < 4; ++c)
    loV[c] = (q32 >> 1) * 256 +
             (((((q32 & 1) << 3) | (c * 2 + hi)) ^ ((q32 >> 1) & 15)) << 4);

  if (w == 0) {
#pragma unroll
    for (int c = 0; c < 4; ++c)
      gload_lds16(maskb + b * 1024 + c * 256 + l * 4, (char*)lM + c * 1024);
  }
#pragma unroll
  for (int c = 0; c < 4; ++c)
    gload_lds16(pgK + soK[c], (char*)lK[0] + w * 4096 + c * 1024);

  float l_ = 0.f;
  f32x16 oacc[4];
#pragma unroll
  for (int i = 0; i < 4; ++i)
#pragma unroll
    for (int r = 0; r < 16; ++r) oacc[i][r] = 0.f;

  const float SCL = 0.04508422f;  // (1/32) * log2(e)
  const char* pM0 = (const char*)lM + hi * 16;

#define STAGE_K(TN, BUF)                                                      \
  {                                                                           \
    const char* pk_ = pgK + (size_t)(TN)*131072;                              \
    _Pragma("unroll")                                                         \
    for (int c = 0; c < 4; ++c)                                               \
      gload_lds16(pk_ + soK[c], (char*)lK[BUF] + w * 4096 + c * 1024);        \
  }
#define STAGE_V(TN)                                                           \
  {                                                                           \
    const char* pv_ = pgV + (size_t)(TN)*128;                                 \
    _Pragma("unroll")                                                         \
    for (int c = 0; c < 4; ++c)                                               \
      gload_lds16(pv_ + soV[c], (char*)lV + w * 4096 + c * 1024);             \
  }

#define ATT_TILE(T, CUR, FIRST, LAST)                                         \
  {                                                                           \
    STAGE_V(T);                                                               \
    if (FIRST) { wait_vm<4>(); barrier_raw(); }                               \
    f32x16 sc[2];                                                             \
    _Pragma("unroll")                                                         \
    for (int kb = 0; kb < 2; ++kb)                                            \
      _Pragma("unroll")                                                       \
      for (int r = 0; r < 16; ++r) sc[kb][r] = 0.f;                           \
    __builtin_amdgcn_s_setprio(1);                                            \
    _Pragma("unroll")                                                         \
    for (int dc = 0; dc < 8; ++dc) {                                          \
      int offk = bK + (((dc * 32) | hib) ^ swzK);                             \
      _Pragma("unroll")                                                       \
      for (int kb = 0; kb < 2; ++kb) {                                        \
        s16x8 kf = *(const s16x8*)((const char*)lK[CUR] + offk + kb * 8192);  \
        sc[kb] = mfma32(kf, qf[dc], sc[kb]);                                  \
      }                                                                       \
    }                                                                         \
    __builtin_amdgcn_s_setprio(0);                                            \
    const char* pMa = pM0 + (T)*256;                                          \
    float rs = 0.f;                                                           \
    _Pragma("unroll")                                                         \
    for (int kb = 0; kb < 2; ++kb) {                                          \
      f32x4 mv[4];                                                            \
      _Pragma("unroll")                                                       \
      for (int g2 = 0; g2 < 4; ++g2)                                          \
        mv[g2] = *(const f32x4*)(pMa + kb * 128 + g2 * 32);                   \
      _Pragma("unroll")                                                       \
      for (int r = 0; r < 16; ++r) {                                          \
        float pe = fexp2(fmaf(sc[kb][r], SCL, mv[r >> 2][r & 3]));            \
        sc[kb][r] = pe;                                                       \
        rs += pe;                                                             \
      }                                                                       \
    }                                                                         \
    rs += __shfl_xor(rs, 32);                                                 \
    l_ += rs;                                                                 \
    if (!(LAST)) STAGE_K((T) + 1, (CUR) ^ 1);                                 \
    if (LAST) wait_vm<0>(); else wait_vm<4>();                                \
    barrier_raw();                                                            \
    _Pragma("unroll")                                                         \
    for (int kc = 0; kc < 4; ++kc) {                                          \
      const int kb = kc >> 1;                                                 \
      const int ra2 = (kc & 1) * 8;                                           \
      u32 x0 = cvtpk_bf16(sc[kb][ra2 + 0], sc[kb][ra2 + 1]);                  \
      u32 x1 = cvtpk_bf16(sc[kb][ra2 + 2], sc[kb][ra2 + 3]);                  \
      u32 y0 = cvtpk_bf16(sc[kb][ra2 + 4], sc[kb][ra2 + 5]);                  \
      u32 y1 = cvtpk_bf16(sc[kb][ra2 + 6], sc[kb][ra2 + 7]);                  \
      asm("v_permlane32_swap_b32 %0, %1" : "+v"(x0), "+v"(y0));               \
      asm("v_permlane32_swap_b32 %0, %1" : "+v"(x1), "+v"(y1));               \
      union { u32 u[4]; s16x8 v; } pa;                                        \
      pa.u[0] = x0; pa.u[1] = x1; pa.u[2] = y0; pa.u[3] = y1;                 \
      __builtin_amdgcn_s_setprio(1);                                          \
      _Pragma("unroll")                                                       \
      for (int nb = 0; nb < 4; ++nb) {                                        \
        s16x8 vb = *(const s16x8*)((const char*)lV + loV[kc] + nb * 4096);    \
        oacc[nb] = mfma32(pa.v, vb, oacc[nb]);                                \
      }                                                                       \
      __builtin_amdgcn_s_setprio(0);                                          \
    }                                                                         \
    if (!(LAST)) { wait_vm<0>(); barrier_raw(); }                             \
  }

  ATT_TILE(0, 0, true, false);
  for (int it = 0; it < 7; ++it) {
    ATT_TILE(2 * it + 1, 1, false, false);
    ATT_TILE(2 * it + 2, 0, false, false);
  }
  ATT_TILE(15, 1, false, true);
#undef ATT_TILE
#undef STAGE_K
#undef STAGE_V

  float inv = (l_ > 1e-20f) ? (1.0f / l_) : 0.f;  // fully-masked row -> 0
  u16* obase = attnO + ((size_t)(b * 1024 + qb * 128 + w * 32)) * 1024 + h * 128;
#pragma unroll
  for (int r = 0; r < 16; ++r) {
    int qr = (r & 3) + 8 * (r >> 2) + 4 * hi;
    float iv = __shfl(inv, qr);
#pragma unroll
    for (int nb = 0; nb < 4; ++nb)
      obase[(size_t)qr * 1024 + nb * 32 + q32] = f2bf(oacc[nb][r] * iv);
  }
}

// ---------------------------------------------------------------------------
// fused residual + LayerNorm over 1024 cols. one block per row.
// ---------------------------------------------------------------------------
__global__ __launch_bounds__(256) void ln_fused(
    const float* __restrict__ aF, const u16* __restrict__ aBF,
    const u16* __restrict__ baddBF, const float* __restrict__ g,
    const float* __restrict__ bt, float* __restrict__ outF,
    u16* __restrict__ outBF) {
  const int row = blockIdx.x;
  const int c = threadIdx.x << 2;
  const size_t base = (size_t)row * 1024 + c;
  float4 h;
  if (aF) {
    h = *(const float4*)(aF + base);
  } else {
    u16x4 u = *(const u16x4*)(aBF + base);
    h.x = bf2f(u[0]); h.y = bf2f(u[1]); h.z = bf2f(u[2]); h.w = bf2f(u[3]);
  }
  if (baddBF) {
    u16x4 u = *(const u16x4*)(baddBF + base);
    h.x += bf2f(u[0]); h.y += bf2f(u[1]); h.z += bf2f(u[2]); h.w += bf2f(u[3]);
  }
  float s = (h.x + h.y) + (h.z + h.w);
  float q = (h.x * h.x + h.y * h.y) + (h.z * h.z + h.w * h.w);
#pragma unroll
  for (int msk = 1; msk < 64; msk <<= 1) {
    s += __shfl_xor(s, msk);
    q += __shfl_xor(q, msk);
  }
  __shared__ float sh[8];
  const int w = threadIdx.x >> 6;
  if ((threadIdx.x & 63) == 0) { sh[w] = s; sh[4 + w] = q; }
  __syncthreads();
  s = (sh[0] + sh[1]) + (sh[2] + sh[3]);
  q = (sh[4] + sh[5]) + (sh[6] + sh[7]);
  const float mu = s * (1.f / 1024.f);
  const float var = q * (1.f / 1024.f) - mu * mu;
  const float rstd = rsqrtf(var + 1e-5f);
  const float4 gv = *(const float4*)(g + c);
  const float4 bv = *(const float4*)(bt + c);
  float4 o;
  o.x = (h.x - mu) * rstd * gv.x + bv.x;
  o.y = (h.y - mu) * rstd * gv.y + bv.y;
  o.z = (h.z - mu) * rstd * gv.z + bv.z;
  o.w = (h.w - mu) * rstd * gv.w + bv.w;
  if (outF) *(float4*)(outF + base) = o;
  if (outBF) {
    u16x4 ub; ub[0] = f2bf(o.x); ub[1] = f2bf(o.y); ub[2] = f2bf(o.z); ub[3] = f2bf(o.w);
    *(u16x4*)(outBF + base) = ub;
  }
}

// ---------------------------------------------------------------------------
extern "C" void kernel_launch(void* const* d_in, const int* in_sizes, int n_in,
                              void* d_out, int out_size, void* d_ws, size_t ws_size,
                              hipStream_t stream) {
  const float* X  = (const float*)d_in[0];
  const float* Y  = (const float*)d_in[1];
  const void*  mask = d_in[2];
  const float* Wq = (const float*)d_in[3];
  const float* bq = (const float*)d_in[4];
  const float* Wk = (const float*)d_in[5];
  const float* bk = (const float*)d_in[6];
  const float* Wv = (const float*)d_in[7];
  const float* bv = (const float*)d_in[8];
  const float* Wo = (const float*)d_in[9];
  const float* bo = (const float*)d_in[10];
  const float* g1 = (const float*)d_in[11];
  const float* b1 = (const float*)d_in[12];
  const float* g2 = (const float*)d_in[13];
  const float* b2 = (const float*)d_in[14];
  float* out = (float*)d_out;

  char* ws = (char*)d_ws;
  const size_t MB = 1024ull * 1024ull;
  u16* Xbf    = (u16*)(ws + 0);         // 16MB, dead after QKV-gemm -> O1bf
  u16* Ybf    = (u16*)(ws + 16 * MB);   // 16MB
  u16* Qbf    = (u16*)(ws + 32 * MB);   // 16MB (alive through LN1)
  u16* Kbf    = (u16*)(ws + 48 * MB);   // 16MB, dead after attn -> Rbf
  u16* Vt     = (u16*)(ws + 64 * MB);   // 16MB
  u16* attnbf = (u16*)(ws + 80 * MB);   // 16MB, dead after LN1
  u16* Wqt = (u16*)(ws + 112 * MB);
  u16* Wkt = (u16*)(ws + 114 * MB);
  u16* Wvt = (u16*)(ws + 116 * MB);
  u16* Wot = (u16*)(ws + 118 * MB);
  float* maskb = (float*)(ws + 120 * MB);  // 32KB
  u16* Rbf = Kbf;
  u16* O1bf = Xbf;

  prep_all<<<dim3(6176), dim3(256), 0, stream>>>(
      X, Xbf, Y, Ybf, Wq, Wk, Wv, Wo, Wqt, Wkt, Wvt, Wot,
      (const u32*)mask, maskb);

  gemm_qkv<<<dim3(768), dim3(256), 0, stream>>>(
      Xbf, Ybf, Wqt, Wkt, Wvt, bq, bk, bv, Qbf, Kbf, Vt);

  attn_fwd<<<dim3(512), dim3(256), 0, stream>>>(Qbf, Kbf, Vt, maskb, attnbf);

  ln_fused<<<dim3(8192), dim3(256), 0, stream>>>(nullptr, Qbf, attnbf, g1, b1, nullptr, O1bf);
  gemm_o<<<dim3(256), dim3(256), 0, stream>>>(O1bf, Wot, bo, Rbf, O1bf);
  ln_fused<<<dim3(8192), dim3(256), 0, stream>>>(nullptr, Rbf, nullptr, g2, b2, out, nullptr);
}

// Round 13
// 165.355 us; speedup vs baseline: 1.1287x; 1.1287x over previous
//
#include <hip/hip_runtime.h>
#include <stdint.h>

// ---------------------------------------------------------------------------
// MAB block: O = LN2(O1 + relu(O1@Wo+bo)), O1 = LN1(Q + MHA(Q,K,V,mask))
// Config: r9 (best measured total) + A-issue hoist in gemm_qkv.
// ---------------------------------------------------------------------------

typedef unsigned short u16;
typedef unsigned int u32;
typedef __attribute__((ext_vector_type(8))) short s16x8;   // bf16x8 frag (4 VGPR)
typedef __attribute__((ext_vector_type(4))) float f32x4;
typedef __attribute__((ext_vector_type(16))) float f32x16; // 32x32 MFMA C/D
typedef __attribute__((ext_vector_type(4))) u16 u16x4;
typedef __attribute__((ext_vector_type(4))) u32 u32x4;

typedef __attribute__((address_space(1))) const void* as1cv;
typedef __attribute__((address_space(3))) void* as3v;

#define DEVINL __device__ __forceinline__

DEVINL u16 f2bf(float f) {
  union { float f; u32 u; } v; v.f = f;
  return (u16)((v.u + 0x7FFFu + ((v.u >> 16) & 1u)) >> 16);  // RNE
}
DEVINL float bf2f(u16 x) {
  union { u32 u; float f; } v; v.u = ((u32)x) << 16;
  return v.f;
}
DEVINL u32 cvtpk_bf16(float lo, float hi) {  // packed RNE f32x2 -> bf16x2
  u32 r;
  asm("v_cvt_pk_bf16_f32 %0, %1, %2" : "=v"(r) : "v"(lo), "v"(hi));
  return r;
}
DEVINL float fexp2(float x) {  // raw v_exp_f32 (2^x)
  float r;
  asm("v_exp_f32 %0, %1" : "=v"(r) : "v"(x));
  return r;
}
DEVINL void gload_lds16(const void* g, void* l) {
  __builtin_amdgcn_global_load_lds((as1cv)g, (as3v)l, 16, 0, 0);
}
DEVINL f32x4 mfma16(s16x8 a, s16x8 b, f32x4 c) {
  return __builtin_amdgcn_mfma_f32_16x16x32_bf16(a, b, c, 0, 0, 0);
}
DEVINL f32x16 mfma32(s16x8 a, s16x8 b, f32x16 c) {
  return __builtin_amdgcn_mfma_f32_32x32x16_bf16(a, b, c, 0, 0, 0);
}
template <int N> DEVINL void wait_vm() {
  asm volatile("s_waitcnt vmcnt(%0)" :: "i"(N) : "memory");
  __builtin_amdgcn_sched_barrier(0);
}
DEVINL void wait_lgkm0() {
  asm volatile("s_waitcnt lgkmcnt(0)" ::: "memory");
  __builtin_amdgcn_sched_barrier(0);
}
DEVINL void barrier_raw() {
  __builtin_amdgcn_sched_barrier(0);
  __builtin_amdgcn_s_barrier();
  __builtin_amdgcn_sched_barrier(0);
}

// ---------------------------------------------------------------------------
// preprocessing (X/Y conversion ELIMINATED -- QKV GEMM reads f32 directly):
//   blocks [0,4096)     : 4x weight transpose+convert W[k][n] -> Wt[n][k]
//   blocks [4096,4128)  : mask prep -> pre-folded softmax bias
// ---------------------------------------------------------------------------
__global__ __launch_bounds__(256) void prep_all(
    const float* __restrict__ W0, const float* __restrict__ W1,
    const float* __restrict__ W2, const float* __restrict__ W3,
    u16* __restrict__ T0, u16* __restrict__ T1,
    u16* __restrict__ T2, u16* __restrict__ T3,
    const u32* __restrict__ mraw, float* __restrict__ maskb) {
  const int bid = blockIdx.x;
  const int t = threadIdx.x;
  if (bid < 4096) {
    const int z = bid >> 10, tile = bid & 1023;
    const int bx = tile & 31, by = tile >> 5;
    const float* W = (z == 0) ? W0 : (z == 1) ? W1 : (z == 2) ? W2 : W3;
    u16* T = (z == 0) ? T0 : (z == 1) ? T1 : (z == 2) ? T2 : T3;
    __shared__ float tl[32][33];
    const int tx = t & 31, ty = t >> 5;
    const int N0 = bx << 5, K0 = by << 5;
#pragma unroll
    for (int i = 0; i < 4; ++i)
      tl[ty + i * 8][tx] = W[(size_t)(K0 + ty + i * 8) * 1024 + N0 + tx];
    __syncthreads();
#pragma unroll
    for (int i = 0; i < 4; ++i)
      T[(size_t)(N0 + ty + i * 8) * 1024 + K0 + tx] = f2bf(tl[tx][ty + i * 8]);
    return;
  }
  // ---- mask prep
  __shared__ int mode;
  int fB = 0, fF = 0;
  for (int i = t; i < 2048; i += 256) {
    u32 v = mraw[i];
    if (v == 0x3F800000u) fF = 1;
    else if (v > 1u) fB = 1;
  }
  if (t == 0) mode = 0;
  __syncthreads();
  if (fB) atomicOr(&mode, 1);
  if (fF) atomicOr(&mode, 2);
  __syncthreads();
  const int md = mode;
  const int idx = (bid - 4096) * 256 + t;
  int v;
  if (md & 1)       v = ((const unsigned char*)mraw)[idx] != 0;
  else if (md & 2)  v = ((const float*)mraw)[idx] != 0.0f;
  else              v = ((const int*)mraw)[idx] != 0;
  maskb[idx] = v ? -3e30f : -11.54156032f;
}

// ---------------------------------------------------------------------------
// merged Q/K/V GEMM, A-operand read DIRECTLY from f32 X/Y (r9 structure):
// per kt: issue 8 global f32x4 A-loads (kt+1) at loop TOP (hoisted for max
// cover); ds_read+MFMA kc0; ds_read kc1; lgkm0+barrier; gload_lds B(kt+1);
// cvt_pk+swizzled ds_write A(kt+1) (compiler waits vmcnt(4) -> B stays in
// flight); MFMA kc1; __syncthreads.
// LDS layout identical to gload_lds version: LDS[row][cb]=src[row][cb^swz].
// 1536 blocks; g = id/512 selects {X@Wq->Qbf, Y@Wk->Kbf, Y@Wv->Vt(transp)}.
// ---------------------------------------------------------------------------
__global__ __launch_bounds__(256, 2) void gemm_qkv(
    const float* __restrict__ X, const float* __restrict__ Y,
    const u16* __restrict__ Wqt, const u16* __restrict__ Wkt,
    const u16* __restrict__ Wvt,
    const float* __restrict__ bq, const float* __restrict__ bk,
    const float* __restrict__ bv,
    u16* __restrict__ Qbf, u16* __restrict__ Kbf, u16* __restrict__ Vt) {
  __shared__ u16 lA[128 * 64];
  __shared__ u16 lB[128 * 64];

  const int id = blockIdx.x;
  const int g = id >> 9;            // 0=Q, 1=K, 2=V
  const int sub = id & 511;
  const int swz = (sub & 7) * 64 + (sub >> 3);   // XCD-contiguous per gemm
  const int mb = swz >> 3;
  const int nb = swz & 7;

  const float* Af = (g == 0) ? X : Y;
  const u16* Bt   = (g == 0) ? Wqt : (g == 1) ? Wkt : Wvt;
  const float* bias = (g == 0) ? bq : (g == 1) ? bk : bv;

  const int tid = threadIdx.x;
  const int w = tid >> 6, l = tid & 63;
  const int wm = w >> 1, wn = w & 1;
  const int lrow = l & 15, lk = l >> 4;

  const int asr = l >> 3;                 // row within 8-row call group
  const int acol = (l & 7) * 32;          // f32 byte col of lane's 32B chunk
  const int acb = (l & 7) * 16;           // bf16 byte col in LDS
  const int bscol = ((l & 7) << 4) ^ (asr << 4);  // pre-swizzled B source col
  const char* gAf = (const char*)Af + (size_t)(mb * 128) * 4096;
  const char* gB  = (const char*)Bt + (size_t)(nb * 128) * 2048;

  f32x4 acc[4][4];
#pragma unroll
  for (int i = 0; i < 4; ++i)
#pragma unroll
    for (int j = 0; j < 4; ++j) acc[i][j] = f32x4{0.f, 0.f, 0.f, 0.f};

#define QKV_A_ISSUE(KT)                                                       \
  _Pragma("unroll")                                                           \
  for (int c = 0; c < 4; ++c) {                                               \
    const char* p = gAf + (size_t)((w * 4 + c) * 8 + asr) * 4096 +            \
                    (size_t)(KT) * 256 + acol;                                \
    ar[c][0] = *(const f32x4*)p;                                              \
    ar[c][1] = *(const f32x4*)(p + 16);                                       \
  }
#define QKV_A_WRITE                                                           \
  _Pragma("unroll")                                                           \
  for (int c = 0; c < 4; ++c) {                                               \
    const int row = (w * 4 + c) * 8 + asr;                                    \
    u32x4 pw;                                                                 \
    pw[0] = cvtpk_bf16(ar[c][0][0], ar[c][0][1]);                             \
    pw[1] = cvtpk_bf16(ar[c][0][2], ar[c][0][3]);                             \
    pw[2] = cvtpk_bf16(ar[c][1][0], ar[c][1][1]);                             \
    pw[3] = cvtpk_bf16(ar[c][1][2], ar[c][1][3]);                             \
    *(u32x4*)((char*)lA + row * 128 + (acb ^ ((row & 7) << 4))) = pw;         \
  }
#define QKV_B_STAGE(KT)                                                       \
  _Pragma("unroll")                                                           \
  for (int c = 0; c < 4; ++c) {                                               \
    const int row = (w * 4 + c) * 8 + asr;                                    \
    gload_lds16(gB + (size_t)row * 2048 + (size_t)(KT) * 128 + bscol,         \
                (char*)lB + (w * 4 + c) * 1024);                              \
  }

  f32x4 ar[4][2];
  // prologue: tile 0
  QKV_A_ISSUE(0)
  QKV_B_STAGE(0)
  QKV_A_WRITE
  __syncthreads();

  for (int kt = 0; kt < 16; ++kt) {
    if (kt < 15) { QKV_A_ISSUE(kt + 1) }   // hoisted: max cover to vm-wait
    s16x8 af0[4], bf0[4], af1[4], bf1[4];
#pragma unroll
    for (int mi = 0; mi < 4; ++mi) {
      int row = wm * 64 + mi * 16 + lrow;
      int off = row * 128 + ((lk * 16) ^ ((row & 7) << 4));
      af0[mi] = *(const s16x8*)((const char*)lA + off);
    }
#pragma unroll
    for (int ni = 0; ni < 4; ++ni) {
      int row = wn * 64 + ni * 16 + lrow;
      int off = row * 128 + ((lk * 16) ^ ((row & 7) << 4));
      bf0[ni] = *(const s16x8*)((const char*)lB + off);
    }
#pragma unroll
    for (int mi = 0; mi < 4; ++mi)
#pragma unroll
      for (int ni = 0; ni < 4; ++ni)
        acc[mi][ni] = mfma16(af0[mi], bf0[ni], acc[mi][ni]);
#pragma unroll
    for (int mi = 0; mi < 4; ++mi) {
      int row = wm * 64 + mi * 16 + lrow;
      int off = row * 128 + ((lk * 16 + 64) ^ ((row & 7) << 4));
      af1[mi] = *(const s16x8*)((const char*)lA + off);
    }
#pragma unroll
    for (int ni = 0; ni < 4; ++ni) {
      int row = wn * 64 + ni * 16 + lrow;
      int off = row * 128 + ((lk * 16 + 64) ^ ((row & 7) << 4));
      bf1[ni] = *(const s16x8*)((const char*)lB + off);
    }
    wait_lgkm0();
    barrier_raw();
    if (kt < 15) {
      QKV_B_STAGE(kt + 1)
      QKV_A_WRITE      // compiler inserts vmcnt(4): A-loads done, B in flight
    }
#pragma unroll
    for (int mi = 0; mi < 4; ++mi)
#pragma unroll
      for (int ni = 0; ni < 4; ++ni)
        acc[mi][ni] = mfma16(af1[mi], bf1[ni], acc[mi][ni]);
    __syncthreads();
  }
#undef QKV_A_ISSUE
#undef QKV_A_WRITE
#undef QKV_B_STAGE

  const int growb = mb * 128 + wm * 64;
  const int gcolb = nb * 128 + wn * 64;
  float bs[4];
#pragma unroll
  for (int ni = 0; ni < 4; ++ni) bs[ni] = bias[gcolb + ni * 16 + lrow];

  if (g == 2) {
#pragma unroll
    for (int mi = 0; mi < 4; ++mi) {
      const int grow0 = growb + mi * 16 + lk * 4;
#pragma unroll
      for (int ni = 0; ni < 4; ++ni) {
        const int gcol = gcolb + ni * 16 + lrow;
        u16x4 pk;
#pragma unroll
        for (int r = 0; r < 4; ++r) pk[r] = f2bf(acc[mi][ni][r] + bs[ni]);
        size_t flat = ((size_t)((grow0 >> 10) << 10) + gcol) * 1024 + (grow0 & 1023);
        *(u16x4*)(Vt + flat) = pk;
      }
    }
  } else {
    u16* outBF = g ? Kbf : Qbf;
#pragma unroll
    for (int mi = 0; mi < 4; ++mi) {
      const int grow0 = growb + mi * 16 + lk * 4;
#pragma unroll
      for (int ni = 0; ni < 4; ++ni) {
        const int gcol = gcolb + ni * 16 + lrow;
#pragma unroll
        for (int r = 0; r < 4; ++r)
          outBF[(size_t)(grow0 + r) * 1024 + gcol] = f2bf(acc[mi][ni][r] + bs[ni]);
      }
    }
  }
}

// ---------------------------------------------------------------------------
// O-projection GEMM (A bf16 via gload_lds, r8 structure):
// outBF = bf16(bf2f(residBF) + relu(acc+bias))
// ---------------------------------------------------------------------------
__global__ __launch_bounds__(256, 2) void gemm_o(
    const u16* __restrict__ A, const u16* __restrict__ Bt,
    const float* __restrict__ bias, u16* __restrict__ outBF,
    const u16* __restrict__ residBF) {
  __shared__ u16 lA[128 * 64];
  __shared__ u16 lB[128 * 64];

  const int id = blockIdx.x;
  const int swz = (id & 7) * 64 + (id >> 3);
  const int mb = swz >> 3;
  const int nb = swz & 7;

  const int tid = threadIdx.x;
  const int w = tid >> 6, l = tid & 63;
  const int wm = w >> 1, wn = w & 1;
  const int lrow = l & 15, lk = l >> 4;
  const int sr = l >> 3;
  const int scol = ((l & 7) << 4) ^ (sr << 4);
  const char* gA = (const char*)A + (size_t)(mb * 128) * 2048;
  const char* gB = (const char*)Bt + (size_t)(nb * 128) * 2048;

  f32x4 acc[4][4];
#pragma unroll
  for (int i = 0; i < 4; ++i)
#pragma unroll
    for (int j = 0; j < 4; ++j) acc[i][j] = f32x4{0.f, 0.f, 0.f, 0.f};

#pragma unroll
  for (int c = 0; c < 4; ++c) {
    int row = (w * 4 + c) * 8 + sr;
    gload_lds16(gA + (size_t)row * 2048 + scol, (char*)lA + (w * 4 + c) * 1024);
    gload_lds16(gB + (size_t)row * 2048 + scol, (char*)lB + (w * 4 + c) * 1024);
  }
  __syncthreads();

  for (int kt = 0; kt < 16; ++kt) {
    s16x8 af0[4], bf0[4], af1[4], bf1[4];
#pragma unroll
    for (int mi = 0; mi < 4; ++mi) {
      int row = wm * 64 + mi * 16 + lrow;
      int off = row * 128 + ((lk * 16) ^ ((row & 7) << 4));
      af0[mi] = *(const s16x8*)((const char*)lA + off);
    }
#pragma unroll
    for (int ni = 0; ni < 4; ++ni) {
      int row = wn * 64 + ni * 16 + lrow;
      int off = row * 128 + ((lk * 16) ^ ((row & 7) << 4));
      bf0[ni] = *(const s16x8*)((const char*)lB + off);
    }
#pragma unroll
    for (int mi = 0; mi < 4; ++mi)
#pragma unroll
      for (int ni = 0; ni < 4; ++ni)
        acc[mi][ni] = mfma16(af0[mi], bf0[ni], acc[mi][ni]);
#pragma unroll
    for (int mi = 0; mi < 4; ++mi) {
      int row = wm * 64 + mi * 16 + lrow;
      int off = row * 128 + ((lk * 16 + 64) ^ ((row & 7) << 4));
      af1[mi] = *(const s16x8*)((const char*)lA + off);
    }
#pragma unroll
    for (int ni = 0; ni < 4; ++ni) {
      int row = wn * 64 + ni * 16 + lrow;
      int off = row * 128 + ((lk * 16 + 64) ^ ((row & 7) << 4));
      bf1[ni] = *(const s16x8*)((const char*)lB + off);
    }
    wait_lgkm0();
    barrier_raw();
    if (kt < 15) {
      const int kb = (kt + 1) * 128;
#pragma unroll
      for (int c = 0; c < 4; ++c) {
        int row = (w * 4 + c) * 8 + sr;
        gload_lds16(gA + (size_t)row * 2048 + kb + scol, (char*)lA + (w * 4 + c) * 1024);
        gload_lds16(gB + (size_t)row * 2048 + kb + scol, (char*)lB + (w * 4 + c) * 1024);
      }
    }
#pragma unroll
    for (int mi = 0; mi < 4; ++mi)
#pragma unroll
      for (int ni = 0; ni < 4; ++ni)
        acc[mi][ni] = mfma16(af1[mi], bf1[ni], acc[mi][ni]);
    __syncthreads();
  }

  const int growb = mb * 128 + wm * 64;
  const int gcolb = nb * 128 + wn * 64;
  float bs[4];
#pragma unroll
  for (int ni = 0; ni < 4; ++ni) bs[ni] = bias[gcolb + ni * 16 + lrow];

#pragma unroll
  for (int mi = 0; mi < 4; ++mi) {
    const int grow0 = growb + mi * 16 + lk * 4;
#pragma unroll
    for (int ni = 0; ni < 4; ++ni) {
      const int gcol = gcolb + ni * 16 + lrow;
#pragma unroll
      for (int r = 0; r < 4; ++r) {
        float v = acc[mi][ni][r] + bs[ni];
        size_t idx = (size_t)(grow0 + r) * 1024 + gcol;
        outBF[idx] = f2bf(bf2f(residBF[idx]) + fmaxf(v, 0.f));
      }
    }
  }
}

// ---------------------------------------------------------------------------
// flash attention v8 (unchanged): counted-vmcnt pipeline, K dbuf + V single-
// buffered pair-interleaved, swapped QK^T 32x32x16, static-max softmax,
// per-chunk P packing, permlane32_swap. grid 512; bh per XCD.
// ---------------------------------------------------------------------------
__global__ __launch_bounds__(256, 2) void attn_fwd(
    const u16* __restrict__ Qbf, const u16* __restrict__ Kbf,
    const u16* __restrict__ Vt, const float* __restrict__ maskb,
    u16* __restrict__ attnO) {
  __shared__ u16 lK[2][64 * 128];  // 2x16KB [key][d] 256B rows, swz (key&15)<<4
  __shared__ u16 lV[128 * 64];     // 16KB pair-interleaved
  __shared__ float lM[1024];       // 4KB pre-folded softmax bias

  const int id = blockIdx.x;
  const int xcd = id & 7, seq = id >> 3;
  const int bh = xcd * 8 + (seq >> 3);   // all qb of a bh stay on one XCD
  const int qb = seq & 7;
  const int b = bh >> 3, h = bh & 7;
  const int tid = threadIdx.x;
  const int w = tid >> 6, l = tid & 63;
  const int q32 = l & 31, hi = l >> 5;

  const u16* Qrow = Qbf + ((size_t)(b * 1024 + qb * 128 + w * 32 + q32)) * 1024 + h * 128;
  s16x8 qf[8];
#pragma unroll
  for (int dc = 0; dc < 8; ++dc) qf[dc] = *(const s16x8*)(Qrow + dc * 16 + hi * 8);

  const int srK = l >> 4, slK = l & 15;
  int soK[4], soV[4];
#pragma unroll
  for (int c = 0; c < 4; ++c) {
    int rowK = (w * 4 + c) * 4 + srK;
    soK[c] = rowK * 2048 + ((slK << 4) ^ ((rowK & 15) << 4));
    int pairid = (w * 4 + c) * 4 + (l >> 4);
    int u = (l & 15) ^ (pairid & 15);
    int d = pairid * 2 + (u >> 3);
    soV[c] = d * 2048 + (u & 7) * 16;   // + t*128 bytes at stage time
  }
  const char* pgK = (const char*)(Kbf + ((size_t)(b * 1024)) * 1024 + h * 128);
  const char* pgV = (const char*)(Vt + ((size_t)(b * 1024 + h * 128)) * 1024);

  const int bK = q32 * 256;
  const int swzK = (q32 & 15) << 4;
  const int hib = hi * 16;
  int loV[4];
#pragma unroll
  for (int c = 0; c < 4; ++c)
    loV[c] = (q32 >> 1) * 256 +
             (((((q32 & 1) << 3) | (c * 2 + hi)) ^ ((q32 >> 1) & 15)) << 4);

  if (w == 0) {
#pragma unroll
    for (int c = 0; c < 4; ++c)
      gload_lds16(maskb + b * 1024 + c * 256 + l * 4, (char*)lM + c * 1024);
  }
#pragma unroll
  for (int c = 0; c < 4; ++c)
    gload_lds16(pgK + soK[c], (char*)lK[0] + w * 4096 + c * 1024);

  float l_ = 0.f;
  f32x16 oacc[4];
#pragma unroll
  for (int i = 0; i < 4; ++i)
#pragma unroll
    for (int r = 0; r < 16; ++r) oacc[i][r] = 0.f;

  const float SCL = 0.04508422f;  // (1/32) * log2(e)
  const char* pM0 = (const char*)lM + hi * 16;

#define STAGE_K(TN, BUF)                                                      \
  {                                                                           \
    const char* pk_ = pgK + (size_t)(TN)*131072;                              \
    _Pragma("unroll")                                                         \
    for (int c = 0; c < 4; ++c)                                               \
      gload_lds16(pk_ + soK[c], (char*)lK[BUF] + w * 4096 + c * 1024);        \
  }
#define STAGE_V(TN)                                                           \
  {                                                                           \
    const char* pv_ = pgV + (size_t)(TN)*128;                                 \
    _Pragma("unroll")                                                         \
    for (int c = 0; c < 4; ++c)                                               \
      gload_lds16(pv_ + soV[c], (char*)lV + w * 4096 + c * 1024);             \
  }

#define ATT_TILE(T, CUR, FIRST, LAST)                                         \
  {                                                                           \
    STAGE_V(T);                                                               \
    if (FIRST) { wait_vm<4>(); barrier_raw(); }                               \
    f32x16 sc[2];                                                             \
    _Pragma("unroll")                                                         \
    for (int kb = 0; kb < 2; ++kb)                                            \
      _Pragma("unroll")                                                       \
      for (int r = 0; r < 16; ++r) sc[kb][r] = 0.f;                           \
    __builtin_amdgcn_s_setprio(1);                                            \
    _Pragma("unroll")                                                         \
    for (int dc = 0; dc < 8; ++dc) {                                          \
      int offk = bK + (((dc * 32) | hib) ^ swzK);                             \
      _Pragma("unroll")                                                       \
      for (int kb = 0; kb < 2; ++kb) {                                        \
        s16x8 kf = *(const s16x8*)((const char*)lK[CUR] + offk + kb * 8192);  \
        sc[kb] = mfma32(kf, qf[dc], sc[kb]);                                  \
      }                                                                       \
    }                                                                         \
    __builtin_amdgcn_s_setprio(0);                                            \
    const char* pMa = pM0 + (T)*256;                                          \
    float rs = 0.f;                                                           \
    _Pragma("unroll")                                                         \
    for (int kb = 0; kb < 2; ++kb) {                                          \
      f32x4 mv[4];                                                            \
      _Pragma("unroll")                                                       \
      for (int g = 0; g < 4; ++g)                                             \
        mv[g] = *(const f32x4*)(pMa + kb * 128 + g * 32);                     \
      _Pragma("unroll")                                                       \
      for (int r = 0; r < 16; ++r) {                                          \
        float pe = fexp2(fmaf(sc[kb][r], SCL, mv[r >> 2][r & 3]));            \
        sc[kb][r] = pe;                                                       \
        rs += pe;                                                             \
      }                                                                       \
    }                                                                         \
    rs += __shfl_xor(rs, 32);                                                 \
    l_ += rs;                                                                 \
    if (!(LAST)) STAGE_K((T) + 1, (CUR) ^ 1);                                 \
    if (LAST) wait_vm<0>(); else wait_vm<4>();                                \
    barrier_raw();                                                            \
    _Pragma("unroll")                                                         \
    for (int kc = 0; kc < 4; ++kc) {                                          \
      const int kb = kc >> 1;                                                 \
      const int ra2 = (kc & 1) * 8;                                           \
      u32 x0 = cvtpk_bf16(sc[kb][ra2 + 0], sc[kb][ra2 + 1]);                  \
      u32 x1 = cvtpk_bf16(sc[kb][ra2 + 2], sc[kb][ra2 + 3]);                  \
      u32 y0 = cvtpk_bf16(sc[kb][ra2 + 4], sc[kb][ra2 + 5]);                  \
      u32 y1 = cvtpk_bf16(sc[kb][ra2 + 6], sc[kb][ra2 + 7]);                  \
      asm("v_permlane32_swap_b32 %0, %1" : "+v"(x0), "+v"(y0));               \
      asm("v_permlane32_swap_b32 %0, %1" : "+v"(x1), "+v"(y1));               \
      union { u32 u[4]; s16x8 v; } pa;                                        \
      pa.u[0] = x0; pa.u[1] = x1; pa.u[2] = y0; pa.u[3] = y1;                 \
      __builtin_amdgcn_s_setprio(1);                                          \
      _Pragma("unroll")                                                       \
      for (int nb = 0; nb < 4; ++nb) {                                        \
        s16x8 vb = *(const s16x8*)((const char*)lV + loV[kc] + nb * 4096);    \
        oacc[nb] = mfma32(pa.v, vb, oacc[nb]);                                \
      }                                                                       \
      __builtin_amdgcn_s_setprio(0);                                          \
    }                                                                         \
    if (!(LAST)) { wait_vm<0>(); barrier_raw(); }                             \
  }

  ATT_TILE(0, 0, true, false);
  for (int it = 0; it < 7; ++it) {
    ATT_TILE(2 * it + 1, 1, false, false);
    ATT_TILE(2 * it + 2, 0, false, false);
  }
  ATT_TILE(15, 1, false, true);
#undef ATT_TILE
#undef STAGE_K
#undef STAGE_V

  float inv = (l_ > 1e-20f) ? (1.0f / l_) : 0.f;  // fully-masked row -> 0
  u16* obase = attnO + ((size_t)(b * 1024 + qb * 128 + w * 32)) * 1024 + h * 128;
#pragma unroll
  for (int r = 0; r < 16; ++r) {
    int qr = (r & 3) + 8 * (r >> 2) + 4 * hi;
    float iv = __shfl(inv, qr);
#pragma unroll
    for (int nb = 0; nb < 4; ++nb)
      obase[(size_t)qr * 1024 + nb * 32 + q32] = f2bf(oacc[nb][r] * iv);
  }
}

// ---------------------------------------------------------------------------
// fused residual + LayerNorm over 1024 cols. one block per row.
// ---------------------------------------------------------------------------
__global__ __launch_bounds__(256) void ln_fused(
    const float* __restrict__ aF, const u16* __restrict__ aBF,
    const u16* __restrict__ baddBF, const float* __restrict__ g,
    const float* __restrict__ bt, float* __restrict__ outF,
    u16* __restrict__ outBF) {
  const int row = blockIdx.x;
  const int c = threadIdx.x << 2;
  const size_t base = (size_t)row * 1024 + c;
  float4 h;
  if (aF) {
    h = *(const float4*)(aF + base);
  } else {
    u16x4 u = *(const u16x4*)(aBF + base);
    h.x = bf2f(u[0]); h.y = bf2f(u[1]); h.z = bf2f(u[2]); h.w = bf2f(u[3]);
  }
  if (baddBF) {
    u16x4 u = *(const u16x4*)(baddBF + base);
    h.x += bf2f(u[0]); h.y += bf2f(u[1]); h.z += bf2f(u[2]); h.w += bf2f(u[3]);
  }
  float s = (h.x + h.y) + (h.z + h.w);
  float q = (h.x * h.x + h.y * h.y) + (h.z * h.z + h.w * h.w);
#pragma unroll
  for (int msk = 1; msk < 64; msk <<= 1) {
    s += __shfl_xor(s, msk);
    q += __shfl_xor(q, msk);
  }
  __shared__ float sh[8];
  const int w = threadIdx.x >> 6;
  if ((threadIdx.x & 63) == 0) { sh[w] = s; sh[4 + w] = q; }
  __syncthreads();
  s = (sh[0] + sh[1]) + (sh[2] + sh[3]);
  q = (sh[4] + sh[5]) + (sh[6] + sh[7]);
  const float mu = s * (1.f / 1024.f);
  const float var = q * (1.f / 1024.f) - mu * mu;
  const float rstd = rsqrtf(var + 1e-5f);
  const float4 gv = *(const float4*)(g + c);
  const float4 bv = *(const float4*)(bt + c);
  float4 o;
  o.x = (h.x - mu) * rstd * gv.x + bv.x;
  o.y = (h.y - mu) * rstd * gv.y + bv.y;
  o.z = (h.z - mu) * rstd * gv.z + bv.z;
  o.w = (h.w - mu) * rstd * gv.w + bv.w;
  if (outF) *(float4*)(outF + base) = o;
  if (outBF) {
    u16x4 ub; ub[0] = f2bf(o.x); ub[1] = f2bf(o.y); ub[2] = f2bf(o.z); ub[3] = f2bf(o.w);
    *(u16x4*)(outBF + base) = ub;
  }
}

// ---------------------------------------------------------------------------
extern "C" void kernel_launch(void* const* d_in, const int* in_sizes, int n_in,
                              void* d_out, int out_size, void* d_ws, size_t ws_size,
                              hipStream_t stream) {
  const float* X  = (const float*)d_in[0];
  const float* Y  = (const float*)d_in[1];
  const void*  mask = d_in[2];
  const float* Wq = (const float*)d_in[3];
  const float* bq = (const float*)d_in[4];
  const float* Wk = (const float*)d_in[5];
  const float* bk = (const float*)d_in[6];
  const float* Wv = (const float*)d_in[7];
  const float* bv = (const float*)d_in[8];
  const float* Wo = (const float*)d_in[9];
  const float* bo = (const float*)d_in[10];
  const float* g1 = (const float*)d_in[11];
  const float* b1 = (const float*)d_in[12];
  const float* g2 = (const float*)d_in[13];
  const float* b2 = (const float*)d_in[14];
  float* out = (float*)d_out;

  char* ws = (char*)d_ws;
  const size_t MB = 1024ull * 1024ull;
  u16* O1bf   = (u16*)(ws + 0);         // 16MB
  u16* Qbf    = (u16*)(ws + 32 * MB);   // 16MB (alive through LN1)
  u16* Kbf    = (u16*)(ws + 48 * MB);   // 16MB, dead after attn -> Rbf
  u16* Vt     = (u16*)(ws + 64 * MB);   // 16MB
  u16* attnbf = (u16*)(ws + 80 * MB);   // 16MB, dead after LN1
  u16* Wqt = (u16*)(ws + 112 * MB);
  u16* Wkt = (u16*)(ws + 114 * MB);
  u16* Wvt = (u16*)(ws + 116 * MB);
  u16* Wot = (u16*)(ws + 118 * MB);
  float* maskb = (float*)(ws + 120 * MB);  // 32KB
  u16* Rbf = Kbf;

  prep_all<<<dim3(4128), dim3(256), 0, stream>>>(
      Wq, Wk, Wv, Wo, Wqt, Wkt, Wvt, Wot, (const u32*)mask, maskb);

  gemm_qkv<<<dim3(1536), dim3(256), 0, stream>>>(
      X, Y, Wqt, Wkt, Wvt, bq, bk, bv, Qbf, Kbf, Vt);

  attn_fwd<<<dim3(512), dim3(256), 0, stream>>>(Qbf, Kbf, Vt, maskb, attnbf);

  ln_fused<<<dim3(8192), dim3(256), 0, stream>>>(nullptr, Qbf, attnbf, g1, b1, nullptr, O1bf);
  gemm_o<<<dim3(512), dim3(256), 0, stream>>>(O1bf, Wot, bo, Rbf, O1bf);
  ln_fused<<<dim3(8192), dim3(256), 0, stream>>>(nullptr, Rbf, nullptr, g2, b2, out, nullptr);
}